// Round 3
// baseline (10356.126 us; speedup 1.0000x reference)
//
#include <hip/hip_runtime.h>
#include <cstdint>
#include <cstddef>

// ---------------- problem constants ----------------
#define T_STEPS 2048
#define NBATCH  64
#define HID     256
#define NGATE   1024            // 4*HID

// recurrent kernel: K=256 = 8 chunks of 32. 6 chunks register-resident B-frags,
// 2 chunks streamed from LDS each step.
#define REC_LDS_BYTES (131072 + 1024)   // 128 KB weights + 2 x 256 f16 h buffers

typedef _Float16 f16x8 __attribute__((ext_vector_type(8)));
typedef float    f32x4 __attribute__((ext_vector_type(4)));

__device__ __forceinline__ unsigned short f2h_bits(float f) {
    _Float16 h = (_Float16)f;
    return __builtin_bit_cast(unsigned short, h);
}
__device__ __forceinline__ float h2f_scalar(unsigned short u) {
    return (float)__builtin_bit_cast(_Float16, u);
}

// ---------------- workspace layout (bytes) ----------------
#define OFF_G    ((size_t)0)            // 131072*1024 fp16 = 268435456 (aliased G0/G1)
#define OFF_Y0   ((size_t)268435456)    // 2048*64*256 fp16 = 67108864
#define OFF_WBR0 ((size_t)335544320)    // 196608 fp16 = 393216 B (reg B-frags, chunks 0..5)
#define OFF_WBR1 ((size_t)335937536)
#define OFF_LWR0 ((size_t)336330752)    // 65536 fp16 = 131072 B (LDS B-frags, chunks 6..7)
#define OFF_LWR1 ((size_t)336461824)
#define OFF_BS0  ((size_t)336592896)    // 262144 B
#define OFF_BS1  ((size_t)336855040)    // 524288 B
#define WS_NEED  ((size_t)337379328)

// ---------------- weight conversion / swizzle ----------------
// WBR: B-fragments for register-resident chunks c=0..5.
//   flat = (((w*16 + tl)*6 + c)*64 + lane)*8 + i
//   tile tig = (tl>>2)*16 + w*4 + (tl&3); n = tig*16 + (lane&15); k = c*32 + (lane>>4)*8 + i
// LWR: B-fragments for LDS chunks cc=0..1 (k = 192 + cc*32 + ...).
//   flat = ((tig*2 + cc)*64 + lane)*8 + i
__global__ void convert_weights(const float* __restrict__ w_ih0, const float* __restrict__ w_hh0,
                                const float* __restrict__ w_ih1, const float* __restrict__ w_hh1,
                                unsigned short* __restrict__ WBR0, unsigned short* __restrict__ WBR1,
                                unsigned short* __restrict__ LWR0, unsigned short* __restrict__ LWR1,
                                unsigned short* __restrict__ BS0, unsigned short* __restrict__ BS1)
{
    int gid = blockIdx.x * blockDim.x + threadIdx.x;
    int gsz = gridDim.x * blockDim.x;
    // WBR (196608 elements per layer)
    for (int s = gid; s < 196608; s += gsz) {
        int i = s & 7, lane = (s >> 3) & 63, r = s >> 9;
        int c = r % 6, t2 = r / 6;
        int tl = t2 & 15, ww = t2 >> 4;
        int tig = (tl >> 2) * 16 + ww * 4 + (tl & 3);
        int n = tig * 16 + (lane & 15);
        int k = c * 32 + ((lane >> 4) << 3) + i;
        WBR0[s] = f2h_bits(w_hh0[k * 1024 + n]);
        WBR1[s] = f2h_bits(w_hh1[k * 1024 + n]);
    }
    // LWR (65536 elements per layer)
    for (int s = gid; s < 65536; s += gsz) {
        int i = s & 7, lane = (s >> 3) & 63, r = s >> 9;
        int cc = r & 1, tig = r >> 1;
        int n = tig * 16 + (lane & 15);
        int k = 192 + cc * 32 + ((lane >> 4) << 3) + i;
        LWR0[s] = f2h_bits(w_hh0[k * 1024 + n]);
        LWR1[s] = f2h_bits(w_hh1[k * 1024 + n]);
    }
    // Bswz layer0: K=128 (KB=4)
    for (int s = gid; s < 131072; s += gsz) {
        int i = s & 7, lane = (s >> 3) & 63, kb = (s >> 9) & 3, n16 = s >> 11;
        int k = kb * 32 + (lane >> 4) * 8 + i;
        int n = n16 * 16 + (lane & 15);
        BS0[s] = f2h_bits(w_ih0[k * 1024 + n]);
    }
    // Bswz layer1: K=256 (KB=8)
    for (int s = gid; s < 262144; s += gsz) {
        int i = s & 7, lane = (s >> 3) & 63, kb = (s >> 9) & 7, n16 = s >> 12;
        int k = kb * 32 + (lane >> 4) * 8 + i;
        int n = n16 * 16 + (lane & 15);
        BS1[s] = f2h_bits(w_ih1[k * 1024 + n]);
    }
}

// ---------------- input-gate GEMM (unchanged from round 2; proven) ----------------
// G stored gate-interleaved: col (gate*256+m) -> position m*4+gate.
template <int KB, int LAYER>
__global__ __launch_bounds__(256) void gemm_in(const float* __restrict__ A32,
                                               const unsigned short* __restrict__ A16,
                                               const unsigned short* __restrict__ Bsw,
                                               const float* __restrict__ bias,
                                               unsigned short* __restrict__ Gout)
{
    const int lane = threadIdx.x & 63;
    const int wave = threadIdx.x >> 6;
    const int nblk = blockIdx.x & 15;
    const int rblk = blockIdx.x >> 4;
    const int r0 = rblk * 128 + wave * 32;
    const int quad = lane >> 4, ln = lane & 15;

    f32x4 acc[2][4];
#pragma unroll
    for (int q = 0; q < 4; q++) {
        float bv = bias[(nblk * 4 + q) * 16 + ln];
#pragma unroll
        for (int mt = 0; mt < 2; mt++) {
            acc[mt][q][0] = bv; acc[mt][q][1] = bv; acc[mt][q][2] = bv; acc[mt][q][3] = bv;
        }
    }
    const int ar0 = r0 + ln, ar1 = r0 + 16 + ln;
    size_t aoff0, aoff1;
    if (LAYER == 0) {
        aoff0 = ((size_t)(ar0 & 63) * 2048 + (size_t)(2047 - (ar0 >> 6))) * 128;
        aoff1 = ((size_t)(ar1 & 63) * 2048 + (size_t)(2047 - (ar1 >> 6))) * 128;
    } else {
        aoff0 = ((size_t)(2047 - (ar0 >> 6)) * 64 + (size_t)(ar0 & 63)) * 256;
        aoff1 = ((size_t)(2047 - (ar1 >> 6)) * 64 + (size_t)(ar1 & 63)) * 256;
    }
#pragma unroll
    for (int kb = 0; kb < KB; kb++) {
        const int k0 = kb * 32 + quad * 8;
        f16x8 a0, a1;
        if (LAYER == 0) {
            const float* p0 = A32 + aoff0 + k0;
            const float* p1 = A32 + aoff1 + k0;
            float4 fa = *(const float4*)(p0);
            float4 fb = *(const float4*)(p0 + 4);
            float4 fc = *(const float4*)(p1);
            float4 fd = *(const float4*)(p1 + 4);
            a0[0] = (_Float16)fa.x; a0[1] = (_Float16)fa.y; a0[2] = (_Float16)fa.z; a0[3] = (_Float16)fa.w;
            a0[4] = (_Float16)fb.x; a0[5] = (_Float16)fb.y; a0[6] = (_Float16)fb.z; a0[7] = (_Float16)fb.w;
            a1[0] = (_Float16)fc.x; a1[1] = (_Float16)fc.y; a1[2] = (_Float16)fc.z; a1[3] = (_Float16)fc.w;
            a1[4] = (_Float16)fd.x; a1[5] = (_Float16)fd.y; a1[6] = (_Float16)fd.z; a1[7] = (_Float16)fd.w;
        } else {
            a0 = *(const f16x8*)(A16 + aoff0 + k0);
            a1 = *(const f16x8*)(A16 + aoff1 + k0);
        }
#pragma unroll
        for (int q = 0; q < 4; q++) {
            f16x8 bq = *(const f16x8*)(Bsw + (((size_t)(nblk * 4 + q) * KB + kb) * 64 + lane) * 8);
            acc[0][q] = __builtin_amdgcn_mfma_f32_16x16x32_f16(a0, bq, acc[0][q], 0, 0, 0);
            acc[1][q] = __builtin_amdgcn_mfma_f32_16x16x32_f16(a1, bq, acc[1][q], 0, 0, 0);
        }
    }
#pragma unroll
    for (int mt = 0; mt < 2; mt++)
#pragma unroll
        for (int q = 0; q < 4; q++)
#pragma unroll
            for (int rg = 0; rg < 4; rg++) {
                int row = r0 + mt * 16 + quad * 4 + rg;
                int col = (nblk * 4 + q) * 16 + ln;
                int swz = ((col & 255) << 2) | (col >> 8);
                Gout[(size_t)row * 1024 + swz] = f2h_bits(acc[mt][q][rg]);
            }
}

// ---------------- persistent recurrent kernel: MFMA GEMV, 1 WG per batch ----------------
// 256 threads, 4 waves, 1 wave/SIMD (512-reg budget, no spill).
// h broadcast into A-frags => all 16 rows of every MFMA D-tile are equal, so each
// lane directly holds gate[col = tig*16 + (lane&15)] in any acc reg. Wave w owns
// tiles tig = g*16 + w*4 + u (g=gate, u=0..3); lane handles unit m = w*64 + lane
// (select u = quad among its 4 accumulators). No shuffles, no layout sensitivity.
template <int LAYER>
__global__ __launch_bounds__(256, 1) void lstm_rec(const unsigned short* __restrict__ G,
                                                   const unsigned short* __restrict__ WBR,
                                                   const unsigned short* __restrict__ LWR,
                                                   unsigned short* __restrict__ Y0,
                                                   float* __restrict__ Out)
{
    extern __shared__ char smem[];
    unsigned short* lds_w  = (unsigned short*)smem;               // 65536 halves (chunks 6,7)
    unsigned short* lds_h0 = (unsigned short*)(smem + 131072);    // 256 f16
    unsigned short* lds_h1 = lds_h0 + 256;

    const int b = blockIdx.x;
    const int tid = threadIdx.x;
    const int w = tid >> 6, lane = tid & 63;
    const int quad = lane >> 4;
    const int m = w * 64 + lane;          // this lane's hidden unit

    // register-resident B-fragments: chunks 0..5, 16 tiles -> 384 regs (AGPR-eligible)
    f16x8 wb[6][16];
#pragma unroll
    for (int tl = 0; tl < 16; tl++)
#pragma unroll
        for (int c = 0; c < 6; c++)
            wb[c][tl] = *(const f16x8*)(WBR + ((((size_t)w * 16 + tl) * 6 + c) * 64 + lane) * 8);

    // stage LDS-resident B-fragments (chunks 6,7): 8192 uint4
    {
        const uint4* src = (const uint4*)LWR;
        uint4* dst = (uint4*)lds_w;
        for (int i = tid; i < 8192; i += 256) dst[i] = src[i];
    }
    lds_h0[tid] = 0;
    float c_state = 0.f, hprev = 0.f;
    __syncthreads();

    const unsigned short* Gp = G + (size_t)b * 1024 + (size_t)m * 4;

    for (int t = 0; t < T_STEPS; ++t) {
        // input gates for THIS step: issued now, consumed at epilogue (same interval)
        uint2 gpk = *(const uint2*)(Gp + (size_t)t * 65536);
        // deferred global store of h_{t-1}: retires during the MFMA chain
        if (t) {
            if (LAYER == 0) Y0[((size_t)(t - 1) * 64 + b) * 256 + m] = f2h_bits(hprev);
            else            Out[((size_t)(t - 1) * 64 + b) * 256 + m] = hprev;
        }
        const unsigned short* hcur = (t & 1) ? lds_h1 : lds_h0;
        // h A-fragments: chunk c -> 16B at h + c*64B + quad*16B (4-addr quad broadcast)
        uint4 hq[8];
#pragma unroll
        for (int c = 0; c < 8; c++)
            hq[c] = *(const uint4*)(hcur + c * 32 + quad * 8);

        f32x4 acc[16];
        {
            f16x8 a0 = __builtin_bit_cast(f16x8, hq[0]);
            f32x4 zero = {0.f, 0.f, 0.f, 0.f};
#pragma unroll
            for (int tl = 0; tl < 16; tl++)
                acc[tl] = __builtin_amdgcn_mfma_f32_16x16x32_f16(a0, wb[0][tl], zero, 0, 0, 0);
        }
#pragma unroll
        for (int c = 1; c < 6; c++) {
            f16x8 a = __builtin_bit_cast(f16x8, hq[c]);
#pragma unroll
            for (int tl = 0; tl < 16; tl++)
                acc[tl] = __builtin_amdgcn_mfma_f32_16x16x32_f16(a, wb[c][tl], acc[tl], 0, 0, 0);
        }
#pragma unroll
        for (int cc = 0; cc < 2; cc++) {
            f16x8 a = __builtin_bit_cast(f16x8, hq[6 + cc]);
#pragma unroll
            for (int tl = 0; tl < 16; tl++) {
                int g = tl >> 2, u = tl & 3;
                int tig = g * 16 + w * 4 + u;
                f16x8 bq = *(const f16x8*)(lds_w + (((size_t)tig * 2 + cc) * 64 + lane) * 8);
                acc[tl] = __builtin_amdgcn_mfma_f32_16x16x32_f16(a, bq, acc[tl], 0, 0, 0);
            }
        }
        // epilogue: lane's unit has u = quad; all rows equal -> use reg 0 of each acc
        float fg, ig, og, gg;
        {
            float x0, x1, x2, x3, lo, hi;
            x0 = acc[0][0];  x1 = acc[1][0];  x2 = acc[2][0];  x3 = acc[3][0];
            lo = (quad & 1) ? x1 : x0; hi = (quad & 1) ? x3 : x2; fg = (quad & 2) ? hi : lo;
            x0 = acc[4][0];  x1 = acc[5][0];  x2 = acc[6][0];  x3 = acc[7][0];
            lo = (quad & 1) ? x1 : x0; hi = (quad & 1) ? x3 : x2; ig = (quad & 2) ? hi : lo;
            x0 = acc[8][0];  x1 = acc[9][0];  x2 = acc[10][0]; x3 = acc[11][0];
            lo = (quad & 1) ? x1 : x0; hi = (quad & 1) ? x3 : x2; og = (quad & 2) ? hi : lo;
            x0 = acc[12][0]; x1 = acc[13][0]; x2 = acc[14][0]; x3 = acc[15][0];
            lo = (quad & 1) ? x1 : x0; hi = (quad & 1) ? x3 : x2; gg = (quad & 2) ? hi : lo;
        }
        fg += h2f_scalar((unsigned short)(gpk.x & 0xffff));
        ig += h2f_scalar((unsigned short)(gpk.x >> 16));
        og += h2f_scalar((unsigned short)(gpk.y & 0xffff));
        gg += h2f_scalar((unsigned short)(gpk.y >> 16));
        float sf = 1.f / (1.f + __expf(-fg));
        float si = 1.f / (1.f + __expf(-ig));
        float so = 1.f / (1.f + __expf(-og));
        float tg = 1.f - 2.f / (1.f + __expf(2.f * gg));
        c_state = sf * c_state + si * tg;
        float tc = 1.f - 2.f / (1.f + __expf(2.f * c_state));
        float h = so * tc;
        hprev = h;
        unsigned short* hn = (t & 1) ? lds_h0 : lds_h1;
        hn[m] = f2h_bits(h);
        __syncthreads();
    }
    // final h store + hn/cn
    if (LAYER == 0) Y0[((size_t)(T_STEPS - 1) * 64 + b) * 256 + m] = f2h_bits(hprev);
    else            Out[((size_t)(T_STEPS - 1) * 64 + b) * 256 + m] = hprev;
    Out[(size_t)33554432 + (size_t)LAYER * 16384 + (size_t)b * 256 + m] = hprev;          // hn
    Out[(size_t)33554432 + 32768 + (size_t)LAYER * 16384 + (size_t)b * 256 + m] = c_state; // cn
}

// ---------------- launch ----------------
extern "C" void kernel_launch(void* const* d_in, const int* in_sizes, int n_in,
                              void* d_out, int out_size, void* d_ws, size_t ws_size,
                              hipStream_t stream)
{
    const float* x     = (const float*)d_in[0];
    const float* w_ih0 = (const float*)d_in[1];
    const float* w_hh0 = (const float*)d_in[2];
    const float* b0    = (const float*)d_in[3];
    const float* w_ih1 = (const float*)d_in[4];
    const float* w_hh1 = (const float*)d_in[5];
    const float* b1    = (const float*)d_in[6];
    float* out = (float*)d_out;

    if (ws_size < WS_NEED) return;  // cannot run correctly; fail loudly

    char* ws = (char*)d_ws;
    unsigned short* G    = (unsigned short*)(ws + OFF_G);
    unsigned short* Y0   = (unsigned short*)(ws + OFF_Y0);
    unsigned short* WBR0 = (unsigned short*)(ws + OFF_WBR0);
    unsigned short* WBR1 = (unsigned short*)(ws + OFF_WBR1);
    unsigned short* LWR0 = (unsigned short*)(ws + OFF_LWR0);
    unsigned short* LWR1 = (unsigned short*)(ws + OFF_LWR1);
    unsigned short* BS0  = (unsigned short*)(ws + OFF_BS0);
    unsigned short* BS1  = (unsigned short*)(ws + OFF_BS1);

    (void)hipFuncSetAttribute(reinterpret_cast<const void*>(&lstm_rec<0>),
                              hipFuncAttributeMaxDynamicSharedMemorySize, REC_LDS_BYTES);
    (void)hipFuncSetAttribute(reinterpret_cast<const void*>(&lstm_rec<1>),
                              hipFuncAttributeMaxDynamicSharedMemorySize, REC_LDS_BYTES);

    convert_weights<<<1024, 256, 0, stream>>>(w_ih0, w_hh0, w_ih1, w_hh1,
                                              WBR0, WBR1, LWR0, LWR1, BS0, BS1);
    gemm_in<4, 0><<<16384, 256, 0, stream>>>(x, nullptr, BS0, b0, G);
    lstm_rec<0><<<64, 256, REC_LDS_BYTES, stream>>>(G, WBR0, LWR0, Y0, out);
    gemm_in<8, 1><<<16384, 256, 0, stream>>>(nullptr, Y0, BS1, b1, G);
    lstm_rec<1><<<64, 256, REC_LDS_BYTES, stream>>>(G, WBR1, LWR1, Y0, out);
}